// Round 6
// baseline (1875.704 us; speedup 1.0000x reference)
//
#include <hip/hip_runtime.h>

#define NB   16
#define NN   2048
#define NPTS (NB * NN)
#define KNB  6

typedef __attribute__((ext_vector_type(8))) short short8;
typedef __attribute__((ext_vector_type(2))) float f32x2;
typedef __attribute__((ext_vector_type(4))) float f32x4;
typedef __attribute__((ext_vector_type(16))) float f32x16;
typedef const __attribute__((address_space(4))) float cfloat;

// ---------------- split-precision + squared-norm + self-term fused prep ----------------
// thread = point row: bf16 hi/lo split, |x|^2, and the neighbor-independent
// MLP self-term A[p][op] = (W1a - W1b)*xi + b1 (from the pre-transposed T).
__device__ __forceinline__ unsigned bf16_rne(float f) {
    unsigned u = __float_as_uint(f);
    return (u + 0x7fffu + ((u >> 16) & 1u)) >> 16;
}

template<int C, int COUT>
__global__ __launch_bounds__(256)
void prep_fused(const float* __restrict__ x, const float* __restrict__ T,
                const float* __restrict__ b1,
                unsigned short* __restrict__ Xhi,
                unsigned short* __restrict__ Xlo,
                float* __restrict__ sq, float* __restrict__ A) {
    const int i = blockIdx.x * 256 + threadIdx.x;
    if (i >= NPTS) return;
    float r[C];
    const float4* rp = (const float4*)(x + (size_t)i * C);
#pragma unroll
    for (int c4 = 0; c4 < C / 4; ++c4) {
        float4 f = rp[c4];
        r[4 * c4] = f.x; r[4 * c4 + 1] = f.y; r[4 * c4 + 2] = f.z; r[4 * c4 + 3] = f.w;
    }
    float s = 0.f;
#pragma unroll
    for (int cc = 0; cc < C; cc += 8) {
        short8 vh, vl;
#pragma unroll
        for (int t = 0; t < 8; ++t) {
            const float f = r[cc + t];
            s = fmaf(f, f, s);
            const unsigned h = bf16_rne(f);
            const float hf = __uint_as_float(h << 16);
            const unsigned l = bf16_rne(f - hf);
            vh[t] = (short)h;
            vl[t] = (short)l;
        }
        *(short8*)(Xhi + (size_t)i * C + cc) = vh;
        *(short8*)(Xlo + (size_t)i * C + cc) = vl;
    }
    sq[i] = s;

    cfloat* Tc  = (cfloat*)(uintptr_t)T;
    cfloat* b1c = (cfloat*)(uintptr_t)b1;
    float* Ap = A + (size_t)i * COUT;
#pragma unroll 2
    for (int oq = 0; oq < COUT / 4; ++oq) {
        float av[4];
#pragma unroll
        for (int rr = 0; rr < 4; ++rr) {
            const int op = oq * 4 + rr;
            cfloat* tr = Tc + (size_t)op * (2 * C);
            float a0 = 0.f, a1 = 0.f, a2 = 0.f, a3 = 0.f;
#pragma unroll
            for (int c = 0; c < C; c += 4) {
                a0 = fmaf(tr[c],     r[c],     a0);
                a1 = fmaf(tr[c + 1], r[c + 1], a1);
                a2 = fmaf(tr[c + 2], r[c + 2], a2);
                a3 = fmaf(tr[c + 3], r[c + 3], a3);
            }
            av[rr] = (a0 + a1) + (a2 + a3) + b1c[op];
        }
        *(float4*)(Ap + oq * 4) = make_float4(av[0], av[1], av[2], av[3]);
    }
}

// ---------------- weight prep: T[o][c<CIN] = W1a[c][o]-W1b[c][o]; T[o][CIN+c] = W1b[c][o] ----
__global__ void prep_w(const float* __restrict__ W10, const float* __restrict__ W11,
                       const float* __restrict__ W12,
                       float* __restrict__ T0, float* __restrict__ T1,
                       float* __restrict__ T2) {
    int t = blockIdx.x * 256 + threadIdx.x;
    if (t < 4096) {
        int o = t >> 6, c = t & 63;          // T0/T2: 64 ops x 64 cols (CIN=32)
        float wb0 = W10[(32 + (c & 31)) * 64 + o];
        T0[o * 64 + c] = (c < 32) ? (W10[c * 64 + o] - wb0) : wb0;
        float wb2 = W12[(32 + (c & 31)) * 64 + o];
        T2[o * 64 + c] = (c < 32) ? (W12[c * 64 + o] - wb2) : wb2;
        int o1 = t >> 7, c1 = t & 127;       // T1: 32 ops x 128 cols (CIN=64)
        float wb1 = W11[(64 + (c1 & 63)) * 32 + o1];
        T1[o1 * 128 + c1] = (c1 < 64) ? (W11[c1 * 32 + o1] - wb1) : wb1;
    }
}

// sorted ascending top-6 insert via pure min/max network (2 VALU / level).
__device__ __forceinline__ void insert6f(float s, float* dl) {
#pragma unroll
    for (int k = 0; k < 6; ++k) {
        const float a = dl[k];
        dl[k] = fminf(s, a);
        s = fmaxf(s, a);
    }
}

// ---------------- MFMA kNN scan (32x32 tiles) ----------------
template<int C, int MINW>
__global__ __launch_bounds__(256, MINW)
void knn_scan(const unsigned short* __restrict__ Xhi,
              const unsigned short* __restrict__ Xlo,
              const float* __restrict__ sqv,
              unsigned* __restrict__ plist) {
    constexpr int KT = C / 16;              // K=16 tiles per product
    const int w    = __builtin_amdgcn_readfirstlane(threadIdx.x >> 6);
    const int bid  = blockIdx.x;
    const int swz  = ((bid & 7) << 7) | (bid >> 3);   // 1024 blocks, 128/XCD
    const int b    = swz >> 6;              // batch (2 per XCD)
    const int sp   = (swz >> 4) & 3;        // candidate quarter
    const int qg   = swz & 15;              // query group of 4 tiles
    const int qt   = qg * 4 + w;            // this wave's query tile (32 q)
    const int lane = threadIdx.x & 63;
    const int q31  = lane & 31;
    const int lh   = lane >> 5;
    const int base = b * NN;
    const int qloc = qt * 32 + q31;         // batch-local query index

    short8 bh[KT], bl[KT];
#pragma unroll
    for (int kt = 0; kt < KT; ++kt) {
        const size_t off = (size_t)(base + qloc) * C + kt * 16 + lh * 8;
        bh[kt] = *(const short8*)(Xhi + off);
        bl[kt] = *(const short8*)(Xlo + off);
    }

    float dl[6];
#pragma unroll
    for (int k = 0; k < 6; ++k) dl[k] = 1e30f;

    const int jbeg   = sp * (NN / 4);
    const int jend   = jbeg + NN / 4;
    const int selfjb = qt * 32;             // only block that can contain self

    short8 ah0[KT], al0[KT], ah1[KT], al1[KT];

#define LOADA(AH, AL, JB) do {                                                 \
    _Pragma("unroll")                                                          \
    for (int kt = 0; kt < KT; ++kt) {                                          \
        const size_t off = (size_t)(base + (JB) + q31) * C + kt * 16 + lh * 8; \
        AH[kt] = *(const short8*)(Xhi + off);                                  \
        AL[kt] = *(const short8*)(Xlo + off);                                  \
    }                                                                          \
} while (0)

#define PROC(AH, AL, JB) do {                                                  \
    f32x16 acc = {0.f};                                                        \
    _Pragma("unroll")                                                          \
    for (int kt = 0; kt < KT; ++kt) {                                          \
        acc = __builtin_amdgcn_mfma_f32_32x32x16_bf16(AH[kt], bh[kt], acc, 0, 0, 0); \
        acc = __builtin_amdgcn_mfma_f32_32x32x16_bf16(AH[kt], bl[kt], acc, 0, 0, 0); \
        acc = __builtin_amdgcn_mfma_f32_32x32x16_bf16(AL[kt], bh[kt], acc, 0, 0, 0); \
    }                                                                          \
    float4 s40 = *(const float4*)(sqv + base + (JB) + lh * 4);                 \
    float4 s41 = *(const float4*)(sqv + base + (JB) + lh * 4 + 8);             \
    float4 s42 = *(const float4*)(sqv + base + (JB) + lh * 4 + 16);            \
    float4 s43 = *(const float4*)(sqv + base + (JB) + lh * 4 + 24);            \
    const float sqr[16] = {s40.x, s40.y, s40.z, s40.w, s41.x, s41.y, s41.z, s41.w, \
                           s42.x, s42.y, s42.z, s42.w, s43.x, s43.y, s43.z, s43.w}; \
    const unsigned ebase = (unsigned)(((JB) - jbeg) >> 1);   /* step*16 */     \
    const bool selfstep = ((JB) == selfjb);                                    \
    _Pragma("unroll")                                                          \
    for (int r = 0; r < 16; ++r) {                                             \
        float sc = fmaf(-2.f, acc[r], sqr[r]);                                 \
        sc = __uint_as_float((__float_as_uint(sc) & 0xFFFFFF00u) |             \
                             (ebase + (unsigned)((r & 3) + 4 * (r >> 2))));    \
        if (selfstep) {                                                        \
            const int rowr = (r & 3) + 8 * (r >> 2) + 4 * lh;                  \
            sc = (rowr == q31) ? 1e30f : sc;                                   \
        }                                                                      \
        insert6f(sc, dl);                                                      \
    }                                                                          \
} while (0)

    LOADA(ah0, al0, jbeg);
    for (int jb = jbeg; jb < jend; jb += 64) {
        LOADA(ah1, al1, jb + 32);
        PROC(ah0, al0, jb);
        const int jn = (jb + 64 < jend) ? jb + 64 : jbeg;   // clamped prefetch
        LOADA(ah0, al0, jn);
        PROC(ah1, al1, jb + 32);
    }
#undef LOADA
#undef PROC

    unsigned* o = plist + (size_t)(base + qloc) * 48 + (sp * 2 + lh) * 6;
#pragma unroll
    for (int k = 0; k < 6; ++k) {
        const unsigned bits = __float_as_uint(dl[k]);
        o[k] = bits ^ ((bits & 0x80000000u) ? 0xFFFFFFFFu : 0x80000000u);
    }
}

// ---------------- exact rescore: approx top-8 -> exact fp32 top-6 ----------------
template<int C>
__global__ __launch_bounds__(256)
void rescore(const float* __restrict__ x, const float* __restrict__ sqv,
             const unsigned* __restrict__ plist, int* __restrict__ nbr) {
    const int i = blockIdx.x * 256 + threadIdx.x;
    if (i >= NPTS) return;
    const unsigned* pr = plist + (size_t)i * 48;

    unsigned long long best[8];
#pragma unroll
    for (int k = 0; k < 8; ++k) best[k] = ~0ull;
    for (int z = 0; z < 8; ++z) {
        const unsigned* p = pr + z * 6;
        for (int e = 0; e < 6; ++e) {
            unsigned long long v = ((unsigned long long)p[e] << 3) | (unsigned)z;
            if (v >= best[7]) break;      // sublist ascending
            best[7] = v;
#pragma unroll
            for (int k = 6; k >= 0; --k) {
                if (best[k + 1] < best[k]) {
                    unsigned long long t = best[k]; best[k] = best[k + 1]; best[k + 1] = t;
                }
            }
        }
    }

    const int base = i & ~(NN - 1);
    float4 qv[C / 4];
    const float4* qp = (const float4*)(x + (size_t)i * C);
#pragma unroll
    for (int t = 0; t < C / 4; ++t) qv[t] = qp[t];

    unsigned long long out6[6];
#pragma unroll
    for (int k = 0; k < 6; ++k) out6[k] = ~0ull;

    for (int m = 0; m < 8; ++m) {
        const unsigned u32k = (unsigned)(best[m] >> 3);
        const int z = (int)(best[m] & 7ull);
        const unsigned orig = (u32k & 0x80000000u) ? (u32k ^ 0x80000000u) : ~u32k;
        const int e = (int)(orig & 255u);
        const int idx = e & 15;
        const int jloc = (z >> 1) * (NN / 4) + (e >> 4) * 32 +
                         (idx & 3) + 8 * (idx >> 2) + (z & 1) * 4;

        const float4* cp = (const float4*)(x + (size_t)(base + jloc) * C);
        float d0 = 0.f, d1 = 0.f, d2 = 0.f, d3 = 0.f;
#pragma unroll
        for (int t = 0; t < C / 4; ++t) {
            float4 a = cp[t];
            d0 = fmaf(a.x, qv[t].x, d0);
            d1 = fmaf(a.y, qv[t].y, d1);
            d2 = fmaf(a.z, qv[t].z, d2);
            d3 = fmaf(a.w, qv[t].w, d3);
        }
        const float s = fmaf(-2.f, (d0 + d1) + (d2 + d3), sqv[base + jloc]);
        unsigned u = __float_as_uint(s);
        u ^= (u & 0x80000000u) ? 0xFFFFFFFFu : 0x80000000u;
        unsigned long long key = ((unsigned long long)u << 11) | (unsigned)jloc;
#pragma unroll
        for (int k = 0; k < 6; ++k) {
            const unsigned long long ok = out6[k];
            const bool c = key < ok;
            out6[k] = c ? key : ok;
            key     = c ? ok  : key;
        }
    }
#pragma unroll
    for (int k = 0; k < 6; ++k)
        nbr[i * KNB + k] = base + (int)(out6[k] & 2047ull);
}

// ---------------- edge MLP kernel (LDS-staged weights + hoisted self-term) ----------------
// block = 384 thr = 6 waves; lane = point; wave = neighbor.
// W1b and W2 are staged to LDS once per block; per-op reads are wave-uniform
// broadcasts (~120cy, batched) instead of the per-op scalar-cache stream
// (~300-900cy L2 round-trips) that R5's PMC showed (VALUBusy 21%, ~900cy
// stall per hidden unit). uacc accumulates as f32x2 -> v_pk_fma_f32.
// A[i] float4 stream is 1-deep prefetched. 6->1 max via LDS tree.
template<int CIN, int COUT, bool RESID, int MINW>
__global__ __launch_bounds__(384, MINW)
void mlp_kernel(const float* __restrict__ xin, const int* __restrict__ nbr,
                const float* __restrict__ A,  const float* __restrict__ T,
                const float* __restrict__ W2, const float* __restrict__ b2,
                const float* __restrict__ resid, float* __restrict__ out) {
    constexpr int RS = COUT + 4;
    __shared__ float Buf[3][64][RS];
    __shared__ float Ws1[COUT][CIN];
    __shared__ float Ws2[COUT][COUT];

    const int tid  = threadIdx.x;
    const int lane = tid & 63;
    const int w    = __builtin_amdgcn_readfirstlane(tid >> 6);  // 0..5
    const int i    = blockIdx.x * 64 + lane;
    const int j    = nbr[i * KNB + w];

    // stage weights (wave-uniform broadcast reads later; no conflicts)
    for (int t = tid; t < COUT * CIN; t += 384) {
        const int o = t / CIN, c = t % CIN;
        Ws1[o][c] = T[(size_t)o * (2 * CIN) + CIN + c];
    }
    for (int t = tid; t < COUT * COUT; t += 384)
        Ws2[t / COUT][t % COUT] = W2[t];

    float xj[CIN];
    {
        const float4* jp = (const float4*)(xin + (size_t)j * CIN);
#pragma unroll
        for (int c4 = 0; c4 < CIN / 4; ++c4) {
            float4 f = jp[c4];
            xj[4 * c4] = f.x; xj[4 * c4 + 1] = f.y;
            xj[4 * c4 + 2] = f.z; xj[4 * c4 + 3] = f.w;
        }
    }
    __syncthreads();

    f32x2 uacc[COUT / 2];
#pragma unroll
    for (int o = 0; o < COUT / 2; ++o) uacc[o] = (f32x2){0.f, 0.f};

    const float* Ap = A + (size_t)i * COUT;
    float4 a4 = *(const float4*)(Ap);

#pragma unroll 2
    for (int oq = 0; oq < COUT / 4; ++oq) {
        float4 a4n = a4;
        if (oq + 1 < COUT / 4) a4n = *(const float4*)(Ap + 4 * (oq + 1));
#pragma unroll
        for (int rr = 0; rr < 4; ++rr) {
            const int op = oq * 4 + rr;
            float h0 = 0.f, h1 = 0.f, h2 = 0.f, h3 = 0.f;
#pragma unroll
            for (int c = 0; c < CIN; c += 4) {
                const float4 wv = *(const float4*)(&Ws1[op][c]);
                h0 = fmaf(wv.x, xj[c],     h0);
                h1 = fmaf(wv.y, xj[c + 1], h1);
                h2 = fmaf(wv.z, xj[c + 2], h2);
                h3 = fmaf(wv.w, xj[c + 3], h3);
            }
            const float aop = rr == 0 ? a4.x : rr == 1 ? a4.y : rr == 2 ? a4.z : a4.w;
            const float h = fmaxf((h0 + h1) + (h2 + h3) + aop, 0.f);
            const f32x2 hv = {h, h};
#pragma unroll
            for (int o4 = 0; o4 < COUT / 4; ++o4) {
                const float4 wv = *(const float4*)(&Ws2[op][o4 * 4]);
                uacc[o4 * 2 + 0] += (f32x2){wv.x, wv.y} * hv;   // v_pk_fma_f32
                uacc[o4 * 2 + 1] += (f32x2){wv.z, wv.w} * hv;
            }
        }
        a4 = a4n;
    }

    if (w >= 3) {
#pragma unroll
        for (int o = 0; o < COUT / 2; ++o) {
            Buf[w - 3][lane][2 * o]     = uacc[o].x;
            Buf[w - 3][lane][2 * o + 1] = uacc[o].y;
        }
    }
    __syncthreads();
    if (w < 3) {
#pragma unroll
        for (int o = 0; o < COUT / 2; ++o) {
            uacc[o].x = fmaxf(uacc[o].x, Buf[w][lane][2 * o]);
            uacc[o].y = fmaxf(uacc[o].y, Buf[w][lane][2 * o + 1]);
        }
    }
    __syncthreads();
    if (w == 1 || w == 2) {
#pragma unroll
        for (int o = 0; o < COUT / 2; ++o) {
            Buf[w][lane][2 * o]     = uacc[o].x;
            Buf[w][lane][2 * o + 1] = uacc[o].y;
        }
    }
    __syncthreads();
    if (w == 0) {
        float* po = out + (size_t)i * COUT;
#pragma unroll
        for (int o = 0; o < COUT; ++o) {
            const float u = (o & 1) ? uacc[o / 2].y : uacc[o / 2].x;
            float v = fmaxf(u, fmaxf(Buf[1][lane][o], Buf[2][lane][o])) + b2[o];
            if (RESID) v += resid[(size_t)i * COUT + o];
            po[o] = fmaxf(v, 0.f);
        }
    }
}

extern "C" void kernel_launch(void* const* d_in, const int* in_sizes, int n_in,
                              void* d_out, int out_size, void* d_ws, size_t ws_size,
                              hipStream_t stream) {
    const float* x    = (const float*)d_in[0];
    const float* W1_0 = (const float*)d_in[2];
    const float* b1_0 = (const float*)d_in[3];
    const float* W2_0 = (const float*)d_in[4];
    const float* b2_0 = (const float*)d_in[5];
    const float* W1_1 = (const float*)d_in[6];
    const float* b1_1 = (const float*)d_in[7];
    const float* W2_1 = (const float*)d_in[8];
    const float* b2_1 = (const float*)d_in[9];
    const float* W1_2 = (const float*)d_in[10];
    const float* b1_2 = (const float*)d_in[11];
    const float* W2_2 = (const float*)d_in[12];
    const float* b2_2 = (const float*)d_in[13];
    float* outp = (float*)d_out;

    // workspace layout
    unsigned* plist = (unsigned*)d_ws;                            // NPTS*48 u32
    float* x0  = (float*)(plist + (size_t)NPTS * 48);             // 32768 x 64
    float* x1  = x0 + (size_t)NPTS * 64;                          // 32768 x 32
    float* sqb = x1 + (size_t)NPTS * 32;                          // 32768
    float* T0  = sqb + NPTS;                                      // 64 x 64
    float* T1  = T0 + 4096;                                       // 32 x 128
    float* T2  = T1 + 4096;                                       // 64 x 64
    unsigned short* Xhi = (unsigned short*)(T2 + 4096);           // 32768 x 64 u16
    unsigned short* Xlo = Xhi + (size_t)NPTS * 64;                // 32768 x 64 u16
    int* nbr = (int*)(Xlo + (size_t)NPTS * 64);                   // 32768 x 6
    float* Abuf = (float*)(nbr + (size_t)NPTS * KNB);             // 32768 x 64

    const int sgrid  = NPTS / 256;
    const int scgrid = 1024;            // 4096 waves of 32q x 512c
    const int pgrid  = NPTS / 64;       // 512 blocks x 384 thr

    prep_w<<<16, 256, 0, stream>>>(W1_0, W1_1, W1_2, T0, T1, T2);

    // ---- layer 0: x (32) -> x0 (64), relu ----
    prep_fused<32, 64><<<sgrid, 256, 0, stream>>>(x, T0, b1_0, Xhi, Xlo, sqb, Abuf);
    knn_scan<32, 4><<<scgrid, 256, 0, stream>>>(Xhi, Xlo, sqb, plist);
    rescore<32><<<sgrid, 256, 0, stream>>>(x, sqb, plist, nbr);
    mlp_kernel<32, 64, false, 2><<<pgrid, 384, 0, stream>>>(x, nbr, Abuf, T0, W2_0, b2_0, nullptr, x0);

    // ---- layer 1: x0 (64) -> x1 (32), relu ----
    prep_fused<64, 32><<<sgrid, 256, 0, stream>>>(x0, T1, b1_1, Xhi, Xlo, sqb, Abuf);
    knn_scan<64, 3><<<scgrid, 256, 0, stream>>>(Xhi, Xlo, sqb, plist);
    rescore<64><<<sgrid, 256, 0, stream>>>(x0, sqb, plist, nbr);
    mlp_kernel<64, 32, false, 2><<<pgrid, 384, 0, stream>>>(x0, nbr, Abuf, T1, W2_1, b2_1, nullptr, x1);

    // ---- layer 2: x1 (32) -> out (64), +x0 residual, relu ----
    prep_fused<32, 64><<<sgrid, 256, 0, stream>>>(x1, T2, b1_2, Xhi, Xlo, sqb, Abuf);
    knn_scan<32, 4><<<scgrid, 256, 0, stream>>>(Xhi, Xlo, sqb, plist);
    rescore<32><<<sgrid, 256, 0, stream>>>(x1, sqb, plist, nbr);
    mlp_kernel<32, 64, true, 2><<<pgrid, 384, 0, stream>>>(x1, nbr, Abuf, T2, W2_2, b2_2, x0, outp);
}

// Round 7
// 582.619 us; speedup vs baseline: 3.2194x; 3.2194x over previous
//
#include <hip/hip_runtime.h>

#define NB   16
#define NN   2048
#define NPTS (NB * NN)
#define KNB  6

typedef __attribute__((ext_vector_type(8))) short short8;
typedef __attribute__((ext_vector_type(4))) float f32x4;
typedef __attribute__((ext_vector_type(16))) float f32x16;
typedef const __attribute__((address_space(4))) float cfloat;

// ---------------- split-precision + squared-norm + self-term fused prep ----------------
// thread = point row: bf16 hi/lo split, |x|^2, and the neighbor-independent
// MLP self-term A[p][op] = (W1a - W1b)*xi + b1 (from the pre-transposed T).
__device__ __forceinline__ unsigned bf16_rne(float f) {
    unsigned u = __float_as_uint(f);
    return (u + 0x7fffu + ((u >> 16) & 1u)) >> 16;
}

template<int C, int COUT>
__global__ __launch_bounds__(256)
void prep_fused(const float* __restrict__ x, const float* __restrict__ T,
                const float* __restrict__ b1,
                unsigned short* __restrict__ Xhi,
                unsigned short* __restrict__ Xlo,
                float* __restrict__ sq, float* __restrict__ A) {
    const int i = blockIdx.x * 256 + threadIdx.x;
    if (i >= NPTS) return;
    float r[C];
    const float4* rp = (const float4*)(x + (size_t)i * C);
#pragma unroll
    for (int c4 = 0; c4 < C / 4; ++c4) {
        float4 f = rp[c4];
        r[4 * c4] = f.x; r[4 * c4 + 1] = f.y; r[4 * c4 + 2] = f.z; r[4 * c4 + 3] = f.w;
    }
    float s = 0.f;
#pragma unroll
    for (int cc = 0; cc < C; cc += 8) {
        short8 vh, vl;
#pragma unroll
        for (int t = 0; t < 8; ++t) {
            const float f = r[cc + t];
            s = fmaf(f, f, s);
            const unsigned h = bf16_rne(f);
            const float hf = __uint_as_float(h << 16);
            const unsigned l = bf16_rne(f - hf);
            vh[t] = (short)h;
            vl[t] = (short)l;
        }
        *(short8*)(Xhi + (size_t)i * C + cc) = vh;
        *(short8*)(Xlo + (size_t)i * C + cc) = vl;
    }
    sq[i] = s;

    cfloat* Tc  = (cfloat*)(uintptr_t)T;
    cfloat* b1c = (cfloat*)(uintptr_t)b1;
    float* Ap = A + (size_t)i * COUT;
#pragma unroll 2
    for (int oq = 0; oq < COUT / 4; ++oq) {
        float av[4];
#pragma unroll
        for (int rr = 0; rr < 4; ++rr) {
            const int op = oq * 4 + rr;
            cfloat* tr = Tc + (size_t)op * (2 * C);
            float a0 = 0.f, a1 = 0.f, a2 = 0.f, a3 = 0.f;
#pragma unroll
            for (int c = 0; c < C; c += 4) {
                a0 = fmaf(tr[c],     r[c],     a0);
                a1 = fmaf(tr[c + 1], r[c + 1], a1);
                a2 = fmaf(tr[c + 2], r[c + 2], a2);
                a3 = fmaf(tr[c + 3], r[c + 3], a3);
            }
            av[rr] = (a0 + a1) + (a2 + a3) + b1c[op];
        }
        *(float4*)(Ap + oq * 4) = make_float4(av[0], av[1], av[2], av[3]);
    }
}

// ---------------- weight prep: T[o][c<CIN] = W1a[c][o]-W1b[c][o]; T[o][CIN+c] = W1b[c][o] ----
__global__ void prep_w(const float* __restrict__ W10, const float* __restrict__ W11,
                       const float* __restrict__ W12,
                       float* __restrict__ T0, float* __restrict__ T1,
                       float* __restrict__ T2) {
    int t = blockIdx.x * 256 + threadIdx.x;
    if (t < 4096) {
        int o = t >> 6, c = t & 63;          // T0/T2: 64 ops x 64 cols (CIN=32)
        float wb0 = W10[(32 + (c & 31)) * 64 + o];
        T0[o * 64 + c] = (c < 32) ? (W10[c * 64 + o] - wb0) : wb0;
        float wb2 = W12[(32 + (c & 31)) * 64 + o];
        T2[o * 64 + c] = (c < 32) ? (W12[c * 64 + o] - wb2) : wb2;
        int o1 = t >> 7, c1 = t & 127;       // T1: 32 ops x 128 cols (CIN=64)
        float wb1 = W11[(64 + (c1 & 63)) * 32 + o1];
        T1[o1 * 128 + c1] = (c1 < 64) ? (W11[c1 * 32 + o1] - wb1) : wb1;
    }
}

// sorted ascending top-6 insert via pure min/max network (2 VALU / level).
__device__ __forceinline__ void insert6f(float s, float* dl) {
#pragma unroll
    for (int k = 0; k < 6; ++k) {
        const float a = dl[k];
        dl[k] = fminf(s, a);
        s = fmaxf(s, a);
    }
}

// ---------------- MFMA kNN scan (32x32 tiles) ----------------
template<int C, int MINW>
__global__ __launch_bounds__(256, MINW)
void knn_scan(const unsigned short* __restrict__ Xhi,
              const unsigned short* __restrict__ Xlo,
              const float* __restrict__ sqv,
              unsigned* __restrict__ plist) {
    constexpr int KT = C / 16;              // K=16 tiles per product
    const int w    = __builtin_amdgcn_readfirstlane(threadIdx.x >> 6);
    const int bid  = blockIdx.x;
    const int swz  = ((bid & 7) << 7) | (bid >> 3);   // 1024 blocks, 128/XCD
    const int b    = swz >> 6;              // batch (2 per XCD)
    const int sp   = (swz >> 4) & 3;        // candidate quarter
    const int qg   = swz & 15;              // query group of 4 tiles
    const int qt   = qg * 4 + w;            // this wave's query tile (32 q)
    const int lane = threadIdx.x & 63;
    const int q31  = lane & 31;
    const int lh   = lane >> 5;
    const int base = b * NN;
    const int qloc = qt * 32 + q31;         // batch-local query index

    short8 bh[KT], bl[KT];
#pragma unroll
    for (int kt = 0; kt < KT; ++kt) {
        const size_t off = (size_t)(base + qloc) * C + kt * 16 + lh * 8;
        bh[kt] = *(const short8*)(Xhi + off);
        bl[kt] = *(const short8*)(Xlo + off);
    }

    float dl[6];
#pragma unroll
    for (int k = 0; k < 6; ++k) dl[k] = 1e30f;

    const int jbeg   = sp * (NN / 4);
    const int jend   = jbeg + NN / 4;
    const int selfjb = qt * 32;             // only block that can contain self

    short8 ah0[KT], al0[KT], ah1[KT], al1[KT];

#define LOADA(AH, AL, JB) do {                                                 \
    _Pragma("unroll")                                                          \
    for (int kt = 0; kt < KT; ++kt) {                                          \
        const size_t off = (size_t)(base + (JB) + q31) * C + kt * 16 + lh * 8; \
        AH[kt] = *(const short8*)(Xhi + off);                                  \
        AL[kt] = *(const short8*)(Xlo + off);                                  \
    }                                                                          \
} while (0)

#define PROC(AH, AL, JB) do {                                                  \
    f32x16 acc = {0.f};                                                        \
    _Pragma("unroll")                                                          \
    for (int kt = 0; kt < KT; ++kt) {                                          \
        acc = __builtin_amdgcn_mfma_f32_32x32x16_bf16(AH[kt], bh[kt], acc, 0, 0, 0); \
        acc = __builtin_amdgcn_mfma_f32_32x32x16_bf16(AH[kt], bl[kt], acc, 0, 0, 0); \
        acc = __builtin_amdgcn_mfma_f32_32x32x16_bf16(AL[kt], bh[kt], acc, 0, 0, 0); \
    }                                                                          \
    float4 s40 = *(const float4*)(sqv + base + (JB) + lh * 4);                 \
    float4 s41 = *(const float4*)(sqv + base + (JB) + lh * 4 + 8);             \
    float4 s42 = *(const float4*)(sqv + base + (JB) + lh * 4 + 16);            \
    float4 s43 = *(const float4*)(sqv + base + (JB) + lh * 4 + 24);            \
    const float sqr[16] = {s40.x, s40.y, s40.z, s40.w, s41.x, s41.y, s41.z, s41.w, \
                           s42.x, s42.y, s42.z, s42.w, s43.x, s43.y, s43.z, s43.w}; \
    const unsigned ebase = (unsigned)(((JB) - jbeg) >> 1);   /* step*16 */     \
    const bool selfstep = ((JB) == selfjb);                                    \
    _Pragma("unroll")                                                          \
    for (int r = 0; r < 16; ++r) {                                             \
        float sc = fmaf(-2.f, acc[r], sqr[r]);                                 \
        sc = __uint_as_float((__float_as_uint(sc) & 0xFFFFFF00u) |             \
                             (ebase + (unsigned)((r & 3) + 4 * (r >> 2))));    \
        if (selfstep) {                                                        \
            const int rowr = (r & 3) + 8 * (r >> 2) + 4 * lh;                  \
            sc = (rowr == q31) ? 1e30f : sc;                                   \
        }                                                                      \
        insert6f(sc, dl);                                                      \
    }                                                                          \
} while (0)

    LOADA(ah0, al0, jbeg);
    for (int jb = jbeg; jb < jend; jb += 64) {
        LOADA(ah1, al1, jb + 32);
        PROC(ah0, al0, jb);
        const int jn = (jb + 64 < jend) ? jb + 64 : jbeg;   // clamped prefetch
        LOADA(ah0, al0, jn);
        PROC(ah1, al1, jb + 32);
    }
#undef LOADA
#undef PROC

    unsigned* o = plist + (size_t)(base + qloc) * 48 + (sp * 2 + lh) * 6;
#pragma unroll
    for (int k = 0; k < 6; ++k) {
        const unsigned bits = __float_as_uint(dl[k]);
        o[k] = bits ^ ((bits & 0x80000000u) ? 0xFFFFFFFFu : 0x80000000u);
    }
}

// ---------------- exact rescore: approx top-8 -> exact fp32 top-6 ----------------
template<int C>
__global__ __launch_bounds__(256)
void rescore(const float* __restrict__ x, const float* __restrict__ sqv,
             const unsigned* __restrict__ plist, int* __restrict__ nbr) {
    const int i = blockIdx.x * 256 + threadIdx.x;
    if (i >= NPTS) return;
    const unsigned* pr = plist + (size_t)i * 48;

    unsigned long long best[8];
#pragma unroll
    for (int k = 0; k < 8; ++k) best[k] = ~0ull;
    for (int z = 0; z < 8; ++z) {
        const unsigned* p = pr + z * 6;
        for (int e = 0; e < 6; ++e) {
            unsigned long long v = ((unsigned long long)p[e] << 3) | (unsigned)z;
            if (v >= best[7]) break;      // sublist ascending
            best[7] = v;
#pragma unroll
            for (int k = 6; k >= 0; --k) {
                if (best[k + 1] < best[k]) {
                    unsigned long long t = best[k]; best[k] = best[k + 1]; best[k + 1] = t;
                }
            }
        }
    }

    const int base = i & ~(NN - 1);
    float4 qv[C / 4];
    const float4* qp = (const float4*)(x + (size_t)i * C);
#pragma unroll
    for (int t = 0; t < C / 4; ++t) qv[t] = qp[t];

    unsigned long long out6[6];
#pragma unroll
    for (int k = 0; k < 6; ++k) out6[k] = ~0ull;

    for (int m = 0; m < 8; ++m) {
        const unsigned u32k = (unsigned)(best[m] >> 3);
        const int z = (int)(best[m] & 7ull);
        const unsigned orig = (u32k & 0x80000000u) ? (u32k ^ 0x80000000u) : ~u32k;
        const int e = (int)(orig & 255u);
        const int idx = e & 15;
        const int jloc = (z >> 1) * (NN / 4) + (e >> 4) * 32 +
                         (idx & 3) + 8 * (idx >> 2) + (z & 1) * 4;

        const float4* cp = (const float4*)(x + (size_t)(base + jloc) * C);
        float d0 = 0.f, d1 = 0.f, d2 = 0.f, d3 = 0.f;
#pragma unroll
        for (int t = 0; t < C / 4; ++t) {
            float4 a = cp[t];
            d0 = fmaf(a.x, qv[t].x, d0);
            d1 = fmaf(a.y, qv[t].y, d1);
            d2 = fmaf(a.z, qv[t].z, d2);
            d3 = fmaf(a.w, qv[t].w, d3);
        }
        const float s = fmaf(-2.f, (d0 + d1) + (d2 + d3), sqv[base + jloc]);
        unsigned u = __float_as_uint(s);
        u ^= (u & 0x80000000u) ? 0xFFFFFFFFu : 0x80000000u;
        unsigned long long key = ((unsigned long long)u << 11) | (unsigned)jloc;
#pragma unroll
        for (int k = 0; k < 6; ++k) {
            const unsigned long long ok = out6[k];
            const bool c = key < ok;
            out6[k] = c ? key : ok;
            key     = c ? ok  : key;
        }
    }
#pragma unroll
    for (int k = 0; k < 6; ++k)
        nbr[i * KNB + k] = base + (int)(out6[k] & 2047ull);
}

// ---------------- edge MLP kernel (output-split, hoisted self-term) ----------------
// block = 768 thr = 12 waves = (2 output-halves x 6 neighbors) x 64 points.
// Per thread (R5's proven no-spill shape): h = relu(A[i][op] + W1b[op]*xj)
// for ALL ops (h duplicated across halves), but uacc covers only COUT/2
// outputs -> fewer regs than R5 AND 2x resident waves (6/SIMD) to hide the
// per-op scalar weight-stream latency (R5 PMC: 21% VALUBusy, ~900cy/op
// stall at 3 waves/SIMD). Weights stay on the scalar pipe (R6's LDS staging
// spilled: VGPR 128 + 2.5GB scratch). 6->1 max via per-half LDS tree.
template<int CIN, int COUT, bool RESID, int MINW>
__global__ __launch_bounds__(768, MINW)
void mlp_kernel(const float* __restrict__ xin, const int* __restrict__ nbr,
                const float* __restrict__ A,  const float* __restrict__ T,
                const float* __restrict__ W2, const float* __restrict__ b2,
                const float* __restrict__ resid, float* __restrict__ out) {
    constexpr int HALF = COUT / 2;
    constexpr int RS = HALF + 4;
    __shared__ float Buf[2][3][64][RS];

    const int tid  = threadIdx.x;
    const int lane = tid & 63;
    const int wv   = __builtin_amdgcn_readfirstlane(tid >> 6);  // 0..11
    const int oh   = wv / 6;                                    // output half
    const int w6   = wv % 6;                                    // neighbor
    const int i    = blockIdx.x * 64 + lane;
    const int j    = nbr[i * KNB + w6];

    float xj[CIN];
    {
        const float4* jp = (const float4*)(xin + (size_t)j * CIN);
#pragma unroll
        for (int c4 = 0; c4 < CIN / 4; ++c4) {
            float4 f = jp[c4];
            xj[4 * c4] = f.x; xj[4 * c4 + 1] = f.y;
            xj[4 * c4 + 2] = f.z; xj[4 * c4 + 3] = f.w;
        }
    }

    float uacc[HALF];
#pragma unroll
    for (int o = 0; o < HALF; ++o) uacc[o] = 0.f;

    cfloat* W1c = (cfloat*)(uintptr_t)T;     // use cols CIN..2CIN (W1b^T)
    cfloat* W2c = (cfloat*)(uintptr_t)W2;
    const float* Ap = A + (size_t)i * COUT;

#pragma unroll 2
    for (int oq = 0; oq < COUT / 4; ++oq) {
        const float4 a4 = *(const float4*)(Ap + 4 * oq);
#pragma unroll
        for (int rr = 0; rr < 4; ++rr) {
            const int op = oq * 4 + rr;
            cfloat* w1r = W1c + (size_t)op * (2 * CIN) + CIN;
            float h0 = 0.f, h1 = 0.f, h2 = 0.f, h3 = 0.f;
#pragma unroll
            for (int c = 0; c < CIN; c += 4) {
                h0 = fmaf(w1r[c],     xj[c],     h0);
                h1 = fmaf(w1r[c + 1], xj[c + 1], h1);
                h2 = fmaf(w1r[c + 2], xj[c + 2], h2);
                h3 = fmaf(w1r[c + 3], xj[c + 3], h3);
            }
            const float aop = rr == 0 ? a4.x : rr == 1 ? a4.y : rr == 2 ? a4.z : a4.w;
            const float h = fmaxf((h0 + h1) + (h2 + h3) + aop, 0.f);
            cfloat* w2r = W2c + (size_t)op * COUT + oh * HALF;
#pragma unroll
            for (int o = 0; o < HALF; ++o)
                uacc[o] = fmaf(w2r[o], h, uacc[o]);
        }
    }

    // per-half 6 -> 1 max tree over neighbor waves
    if (w6 >= 3) {
#pragma unroll
        for (int o = 0; o < HALF; ++o) Buf[oh][w6 - 3][lane][o] = uacc[o];
    }
    __syncthreads();
    if (w6 < 3) {
#pragma unroll
        for (int o = 0; o < HALF; ++o) uacc[o] = fmaxf(uacc[o], Buf[oh][w6][lane][o]);
    }
    __syncthreads();
    if (w6 == 1 || w6 == 2) {
#pragma unroll
        for (int o = 0; o < HALF; ++o) Buf[oh][w6][lane][o] = uacc[o];
    }
    __syncthreads();
    if (w6 == 0) {
        float* po = out + (size_t)i * COUT + oh * HALF;
        const float* b2p = b2 + oh * HALF;
#pragma unroll
        for (int o = 0; o < HALF; ++o) {
            float v = fmaxf(uacc[o], fmaxf(Buf[oh][1][lane][o], Buf[oh][2][lane][o])) + b2p[o];
            if (RESID) v += resid[(size_t)i * COUT + oh * HALF + o];
            po[o] = fmaxf(v, 0.f);
        }
    }
}

extern "C" void kernel_launch(void* const* d_in, const int* in_sizes, int n_in,
                              void* d_out, int out_size, void* d_ws, size_t ws_size,
                              hipStream_t stream) {
    const float* x    = (const float*)d_in[0];
    const float* W1_0 = (const float*)d_in[2];
    const float* b1_0 = (const float*)d_in[3];
    const float* W2_0 = (const float*)d_in[4];
    const float* b2_0 = (const float*)d_in[5];
    const float* W1_1 = (const float*)d_in[6];
    const float* b1_1 = (const float*)d_in[7];
    const float* W2_1 = (const float*)d_in[8];
    const float* b2_1 = (const float*)d_in[9];
    const float* W1_2 = (const float*)d_in[10];
    const float* b1_2 = (const float*)d_in[11];
    const float* W2_2 = (const float*)d_in[12];
    const float* b2_2 = (const float*)d_in[13];
    float* outp = (float*)d_out;

    // workspace layout
    unsigned* plist = (unsigned*)d_ws;                            // NPTS*48 u32
    float* x0  = (float*)(plist + (size_t)NPTS * 48);             // 32768 x 64
    float* x1  = x0 + (size_t)NPTS * 64;                          // 32768 x 32
    float* sqb = x1 + (size_t)NPTS * 32;                          // 32768
    float* T0  = sqb + NPTS;                                      // 64 x 64
    float* T1  = T0 + 4096;                                       // 32 x 128
    float* T2  = T1 + 4096;                                       // 64 x 64
    unsigned short* Xhi = (unsigned short*)(T2 + 4096);           // 32768 x 64 u16
    unsigned short* Xlo = Xhi + (size_t)NPTS * 64;                // 32768 x 64 u16
    int* nbr = (int*)(Xlo + (size_t)NPTS * 64);                   // 32768 x 6
    float* Abuf = (float*)(nbr + (size_t)NPTS * KNB);             // 32768 x 64

    const int sgrid  = NPTS / 256;
    const int scgrid = 1024;            // 4096 waves of 32q x 512c
    const int pgrid  = NPTS / 64;       // 512 blocks x 768 thr

    prep_w<<<16, 256, 0, stream>>>(W1_0, W1_1, W1_2, T0, T1, T2);

    // ---- layer 0: x (32) -> x0 (64), relu ----
    prep_fused<32, 64><<<sgrid, 256, 0, stream>>>(x, T0, b1_0, Xhi, Xlo, sqb, Abuf);
    knn_scan<32, 4><<<scgrid, 256, 0, stream>>>(Xhi, Xlo, sqb, plist);
    rescore<32><<<sgrid, 256, 0, stream>>>(x, sqb, plist, nbr);
    mlp_kernel<32, 64, false, 5><<<pgrid, 768, 0, stream>>>(x, nbr, Abuf, T0, W2_0, b2_0, nullptr, x0);

    // ---- layer 1: x0 (64) -> x1 (32), relu ----
    prep_fused<64, 32><<<sgrid, 256, 0, stream>>>(x0, T1, b1_1, Xhi, Xlo, sqb, Abuf);
    knn_scan<64, 3><<<scgrid, 256, 0, stream>>>(Xhi, Xlo, sqb, plist);
    rescore<64><<<sgrid, 256, 0, stream>>>(x0, sqb, plist, nbr);
    mlp_kernel<64, 32, false, 4><<<pgrid, 768, 0, stream>>>(x0, nbr, Abuf, T1, W2_1, b2_1, nullptr, x1);

    // ---- layer 2: x1 (32) -> out (64), +x0 residual, relu ----
    prep_fused<32, 64><<<sgrid, 256, 0, stream>>>(x1, T2, b1_2, Xhi, Xlo, sqb, Abuf);
    knn_scan<32, 4><<<scgrid, 256, 0, stream>>>(Xhi, Xlo, sqb, plist);
    rescore<32><<<sgrid, 256, 0, stream>>>(x1, sqb, plist, nbr);
    mlp_kernel<32, 64, true, 5><<<pgrid, 768, 0, stream>>>(x1, nbr, Abuf, T2, W2_2, b2_2, x0, outp);
}